// Round 1
// baseline (549.115 us; speedup 1.0000x reference)
//
#include <hip/hip_runtime.h>
#include <cstddef>

// ---------------- problem constants ----------------
constexpr int BATCH = 4096;
constexpr int ITEM_COLS = 10242;

// fused-table row offsets
constexpr int R_GENDER = 0;      // 98 rows
constexpr int R_AGE    = 98;     // 7
constexpr int R_OCC    = 105;    // 21
constexpr int R_AREA   = 126;    // 3402
constexpr int R_RATE   = 3528;   // 6
constexpr int R_GENRE  = 3534;   // 25
constexpr int R_DIR    = 3559;   // 2186
constexpr int R_ACTOR  = 5745;   // 8030
constexpr int R_TOTAL  = 13775;

// workspace layout (floats)
constexpr size_t OFF_F   = 0;                              // 13775*64
constexpr size_t OFF_NEW = OFF_F + (size_t)R_TOTAL * 64;   // 64
constexpr size_t OFF_X   = OFF_NEW + 64;                   // 4096*64
constexpr size_t OFF_Y   = OFF_X + (size_t)BATCH * 64;     // 4096*64
constexpr size_t OFF_P   = OFF_Y + (size_t)BATCH * 64;     // 9*4096*64
constexpr size_t OFF_C   = OFF_P + 9ull * BATCH * 64;      // 9*4096
constexpr size_t OFF_SP  = OFF_C + 9ull * BATCH;           // 64*4*64
constexpr size_t OFF_PB  = OFF_SP + 64ull * 4 * 64;        // 4*64
constexpr size_t OFF_SC  = OFF_PB + 4ull * 64;             // 4*4096

// item-column chunk boundaries (segment-aligned): genre | dir x2 | actor x6
__device__ const int CSTARTS[10] = {1, 26, 1119, 2212, 3550, 4888, 6227, 7565, 8903, 10242};

__device__ __forceinline__ float lrelu(float v) { return v >= 0.0f ? v : 0.01f * v; }

// ---------------- K1: fuse embedding tables with projection blocks ----------------
__global__ void k_fuse(const float* __restrict__ gender_tab, const float* __restrict__ age_tab,
                       const float* __restrict__ occ_tab, const float* __restrict__ area_tab,
                       const float* __restrict__ user_W, const float* __restrict__ rate_tab,
                       const float* __restrict__ genre_W, const float* __restrict__ director_W,
                       const float* __restrict__ actor_W, const float* __restrict__ item_W,
                       const float* __restrict__ edges_tab, const float* __restrict__ edge_W,
                       float* __restrict__ F, float* __restrict__ NEWt) {
    int r = blockIdx.x;
    int n = threadIdx.x;
    if (r == R_TOTAL) {
        // new = lrelu((edges_tab[0]*0.12) @ edge_W), one table row
        float acc = 0.0f;
        for (int k = 0; k < 64; ++k)
            acc = fmaf(edges_tab[k] * 0.12f, edge_W[k * 64 + n], acc);
        NEWt[n] = lrelu(acc);
        return;
    }
    const float* src;
    const float* W;
    if (r < R_AGE)        { src = gender_tab  + (size_t)r * 64;              W = user_W;            }
    else if (r < R_OCC)   { src = age_tab     + (size_t)(r - R_AGE) * 64;    W = user_W + 64 * 64;  }
    else if (r < R_AREA)  { src = occ_tab     + (size_t)(r - R_OCC) * 64;    W = user_W + 128 * 64; }
    else if (r < R_RATE)  { src = area_tab    + (size_t)(r - R_AREA) * 64;   W = user_W + 192 * 64; }
    else if (r < R_GENRE) { src = rate_tab    + (size_t)(r - R_RATE) * 64;   W = item_W;            }
    else if (r < R_DIR)   { src = genre_W     + (size_t)(r - R_GENRE) * 64;  W = item_W + 64 * 64;  }
    else if (r < R_ACTOR) { src = director_W  + (size_t)(r - R_DIR) * 64;    W = item_W + 128 * 64; }
    else                  { src = actor_W     + (size_t)(r - R_ACTOR) * 64;  W = item_W + 192 * 64; }
    float acc = 0.0f;
    for (int k = 0; k < 64; ++k)
        acc = fmaf(src[k], W[k * 64 + n], acc);
    F[(size_t)r * 64 + n] = acc;
}

// ---------------- K2: user embedding x (pure gathers after fusing) ----------------
__global__ void k_user(const int* __restrict__ user_emb, const float* __restrict__ F,
                       const float* __restrict__ user_b, float* __restrict__ X) {
    int t = threadIdx.x;
    int b = blockIdx.x * 4 + (t >> 6);
    int n = t & 63;
    const int* ue = user_emb + (size_t)b * 4;
    float v = F[(size_t)(R_GENDER + ue[0]) * 64 + n]
            + F[(size_t)(R_AGE    + ue[1]) * 64 + n]
            + F[(size_t)(R_OCC    + ue[2]) * 64 + n]
            + F[(size_t)(R_AREA   + ue[3]) * 64 + n]
            + user_b[n];
    X[(size_t)b * 64 + n] = v * 0.12f;
}

// ---------------- K3: main multi-hot GEMM, per-chunk partials + counts ----------------
// block = 256 (4 waves); tile = 64 batch rows; lane <-> row, wave <-> 16-col n-slice.
__global__ __launch_bounds__(256) void k_item(const int* __restrict__ item,
                                              const float* __restrict__ F,
                                              float* __restrict__ P, float* __restrict__ C) {
    const int mt = blockIdx.x, ch = blockIdx.y;
    const int cstart = CSTARTS[ch];
    const int len = CSTARTS[ch + 1] - cstart;
    const int t = threadIdx.x;
    const int lane = t & 63;
    const int wv = __builtin_amdgcn_readfirstlane(t >> 6);  // force wave-uniform -> s_loads for W
    const int m0 = mt * 64;

    __shared__ float tile[64 * 65];  // +1 pad: 2-way (free) bank access both sides

    float acc[16];
#pragma unroll
    for (int j = 0; j < 16; ++j) acc[j] = 0.0f;
    float cnt = 0.0f;

    for (int kb = 0; kb < len; kb += 64) {
        int klen = min(64, len - kb);
        __syncthreads();
        // stage 64 rows x 64 cols, coalesced scalar loads, convert to float
#pragma unroll
        for (int it = 0; it < 16; ++it) {
            int f = it * 256 + t;
            int r = f >> 6, kk = f & 63;
            float v = 0.0f;
            if (kk < klen)
                v = (float)item[(size_t)(m0 + r) * ITEM_COLS + cstart + kb + kk];
            tile[r * 65 + kk] = v;
        }
        __syncthreads();
        const float* wbase = F + ((size_t)(3533 + cstart + kb)) * 64 + wv * 16;
        for (int k = 0; k < klen; ++k) {
            float v = tile[lane * 65 + k];
            const float* w = wbase + (size_t)k * 64;
#pragma unroll
            for (int j = 0; j < 16; ++j) acc[j] = fmaf(v, w[j], acc[j]);
            if (wv == 0) cnt += v;  // per-lane exact segment count (wave-uniform branch)
        }
    }
    float* prow = P + ((size_t)ch * BATCH + m0 + lane) * 64 + wv * 16;
#pragma unroll
    for (int j = 0; j < 16; ++j) prow[j] = acc[j];
    if (t < 64) C[(size_t)ch * BATCH + m0 + lane] = cnt;
}

// ---------------- K4: finalize y, per-row dots, per-block s-partials ----------------
__device__ __forceinline__ float wred(float v) {
#pragma unroll
    for (int m = 1; m < 64; m <<= 1) v += __shfl_xor(v, m, 64);
    return v;
}

__global__ __launch_bounds__(256) void k_mid(const int* __restrict__ item, const int* __restrict__ edge_emb,
                                             const float* __restrict__ F, const float* __restrict__ X,
                                             const float* __restrict__ P, const float* __restrict__ C,
                                             const float* __restrict__ item_b, const float* __restrict__ edges_tab,
                                             const float* __restrict__ uu_w, const float* __restrict__ ui_w,
                                             const float* __restrict__ iu_w, const float* __restrict__ ii_w,
                                             float* __restrict__ Y, float* __restrict__ SC,
                                             float* __restrict__ SP) {
    const int t = threadIdx.x;
    const int n = t & 63;
    const int wv = __builtin_amdgcn_readfirstlane(t >> 6);
    const float uuw = uu_w[n], uiw = ui_w[n], iuw = iu_w[n], iiw = ii_w[n];
    const float ib = item_b[n];
    const size_t cs = (size_t)BATCH * 64;
    float s1 = 0.0f, s2 = 0.0f, s3 = 0.0f, s4 = 0.0f;

    for (int i = 0; i < 16; ++i) {
        int b = blockIdx.x * 64 + wv * 16 + i;
        int ri = item[(size_t)b * ITEM_COLS];  // rate index (col 0)
        size_t base = (size_t)b * 64 + n;
        float sg = P[base];
        float sd = P[base + cs] + P[base + 2 * cs];
        float sa = P[base + 3 * cs] + P[base + 4 * cs] + P[base + 5 * cs]
                 + P[base + 6 * cs] + P[base + 7 * cs] + P[base + 8 * cs];
        float cg = C[b];
        float cd = C[BATCH + b] + C[2 * BATCH + b];
        float ca = C[3 * BATCH + b] + C[4 * BATCH + b] + C[5 * BATCH + b]
                 + C[6 * BATCH + b] + C[7 * BATCH + b] + C[8 * BATCH + b];
        float y = (F[(size_t)(R_RATE + ri) * 64 + n] + sg / cg + sd / cd + sa / ca + ib) * 0.12f;
        Y[(size_t)b * 64 + n] = y;
        float x = X[(size_t)b * 64 + n];
        float e = edges_tab[(size_t)edge_emb[b] * 64 + n] * 0.12f;
        float xe = x * e, ye = y * e;
        float r1 = wred(xe * uuw);  // x_xx
        float r2 = wred(xe * uiw);  // x_xy_x
        float r3 = wred(xe * iuw);  // y_yx_x
        float r4 = wred(ye * uiw);  // x_xy_y
        float r5 = wred(ye * iiw);  // y_yy
        float r6 = wred(ye * iuw);  // y_yx_y
        if (n == 0) {
            SC[b] = r1; SC[BATCH + b] = r2; SC[2 * BATCH + b] = r5; SC[3 * BATCH + b] = r6;
        }
        s1 = fmaf(r1, x, s1);  // s1[n] = sum_b x_xx * x
        s2 = fmaf(r4, y, s2);  // s2[n] = sum_b x_xy_y * y
        s3 = fmaf(r5, y, s3);  // s3[n] = sum_b y_yy * y
        s4 = fmaf(r3, x, s4);  // s4[n] = sum_b y_yx_x * x
    }
    __shared__ float sp[4][4][64];
    sp[wv][0][n] = s1; sp[wv][1][n] = s2; sp[wv][2][n] = s3; sp[wv][3][n] = s4;
    __syncthreads();
    int i2 = t >> 6;
    float v = sp[0][i2][n] + sp[1][i2][n] + sp[2][i2][n] + sp[3][i2][n];
    SP[(size_t)blockIdx.x * 256 + t] = v;
}

// ---------------- K4b: reduce s-partials, compute p1..p4 ----------------
__global__ void k_red(const float* __restrict__ SP, const float* __restrict__ uu_W1,
                      const float* __restrict__ ui_W1, const float* __restrict__ iu_W1,
                      const float* __restrict__ ii_W1, float* __restrict__ PB) {
    int t = threadIdx.x;
    int i = t >> 6, n = t & 63;
    float s = 0.0f;
    for (int w = 0; w < 64; ++w) s += SP[(size_t)w * 256 + i * 64 + n];
    __shared__ float sl[4][64];
    sl[i][n] = s;
    __syncthreads();
    const float* W1 = (i == 0) ? uu_W1 : (i == 1) ? ui_W1 : (i == 2) ? ii_W1 : iu_W1;
    float p = 0.0f;
    for (int k = 0; k < 64; ++k) p = fmaf(sl[i][k], W1[k * 64 + n], p);
    PB[i * 64 + n] = p;
}

// ---------------- K5: final outputs ----------------
__global__ void k_out(const float* __restrict__ X, const float* __restrict__ Y,
                      const float* __restrict__ SC, const float* __restrict__ PB,
                      const float* __restrict__ NEWt, const float* __restrict__ edges_tab,
                      const int* __restrict__ edge_emb, float* __restrict__ out) {
    int t = threadIdx.x;
    int b = blockIdx.x * 4 + (t >> 6);
    int n = t & 63;
    float xx = SC[b], xyx = SC[BATCH + b], yy = SC[2 * BATCH + b], yxy = SC[3 * BATCH + b];
    float p1 = PB[n], p2 = PB[64 + n], p3 = PB[128 + n], p4 = PB[192 + n];
    float x = X[(size_t)b * 64 + n], y = Y[(size_t)b * 64 + n];
    float o1 = ((lrelu(xx * p1) + lrelu(xyx * p2)) * 0.5f + x) * 0.5f;
    float o2 = ((lrelu(yy * p3) + lrelu(yxy * p4)) * 0.5f + y) * 0.5f;
    int ei = edge_emb[b];
    float e = edges_tab[(size_t)ei * 64 + n] * 0.12f;
    float o3 = (NEWt[(size_t)ei * 64 + n] + e) * 0.5f;
    out[(size_t)b * 64 + n] = o1;
    out[((size_t)BATCH + b) * 64 + n] = o2;
    out[((size_t)2 * BATCH + b) * 64 + n] = o3;
}

// ---------------- launch ----------------
extern "C" void kernel_launch(void* const* d_in, const int* in_sizes, int n_in,
                              void* d_out, int out_size, void* d_ws, size_t ws_size,
                              hipStream_t stream) {
    (void)in_sizes; (void)n_in; (void)out_size; (void)ws_size;
    const int*   user_emb   = (const int*)  d_in[0];
    const int*   item_emb   = (const int*)  d_in[1];
    const int*   edge_emb   = (const int*)  d_in[2];
    const float* gender_tab = (const float*)d_in[3];
    const float* age_tab    = (const float*)d_in[4];
    const float* occ_tab    = (const float*)d_in[5];
    const float* area_tab   = (const float*)d_in[6];
    const float* user_W     = (const float*)d_in[7];
    const float* user_b     = (const float*)d_in[8];
    const float* rate_tab   = (const float*)d_in[9];
    const float* genre_W    = (const float*)d_in[10];
    const float* director_W = (const float*)d_in[11];
    const float* actor_W    = (const float*)d_in[12];
    const float* item_W     = (const float*)d_in[13];
    const float* item_b     = (const float*)d_in[14];
    const float* edges_tab  = (const float*)d_in[15];
    const float* uu_w       = (const float*)d_in[16];
    const float* ui_w       = (const float*)d_in[17];
    const float* iu_w       = (const float*)d_in[18];
    const float* ii_w       = (const float*)d_in[19];
    const float* edge_W     = (const float*)d_in[20];
    const float* uu_W1      = (const float*)d_in[21];
    const float* ui_W1      = (const float*)d_in[22];
    const float* iu_W1      = (const float*)d_in[23];
    const float* ii_W1      = (const float*)d_in[24];

    float* ws = (float*)d_ws;
    float* F    = ws + OFF_F;
    float* NEWt = ws + OFF_NEW;
    float* X    = ws + OFF_X;
    float* Y    = ws + OFF_Y;
    float* P    = ws + OFF_P;
    float* C    = ws + OFF_C;
    float* SP   = ws + OFF_SP;
    float* PB   = ws + OFF_PB;
    float* SC   = ws + OFF_SC;
    float* out  = (float*)d_out;

    hipLaunchKernelGGL(k_fuse, dim3(R_TOTAL + 1), dim3(64), 0, stream,
                       gender_tab, age_tab, occ_tab, area_tab, user_W, rate_tab,
                       genre_W, director_W, actor_W, item_W, edges_tab, edge_W, F, NEWt);
    hipLaunchKernelGGL(k_user, dim3(BATCH / 4), dim3(256), 0, stream, user_emb, F, user_b, X);
    hipLaunchKernelGGL(k_item, dim3(BATCH / 64, 9), dim3(256), 0, stream, item_emb, F, P, C);
    hipLaunchKernelGGL(k_mid, dim3(BATCH / 64), dim3(256), 0, stream,
                       item_emb, edge_emb, F, X, P, C, item_b, edges_tab,
                       uu_w, ui_w, iu_w, ii_w, Y, SC, SP);
    hipLaunchKernelGGL(k_red, dim3(1), dim3(256), 0, stream, SP, uu_W1, ui_W1, iu_W1, ii_W1, PB);
    hipLaunchKernelGGL(k_out, dim3(BATCH / 4), dim3(256), 0, stream,
                       X, Y, SC, PB, NEWt, edges_tab, edge_emb, out);
}

// Round 2
// 354.970 us; speedup vs baseline: 1.5469x; 1.5469x over previous
//
#include <hip/hip_runtime.h>
#include <cstddef>

// ---------------- problem constants ----------------
constexpr int BATCH = 4096;
constexpr int ITEM_COLS = 10242;
constexpr int FBTK = 10304;          // Fbt padded K (cols), multiple of 64

// Fu row offsets (fp32 fused table: user fields + rate)
constexpr int R_GENDER = 0;      // 98 rows
constexpr int R_AGE    = 98;     // 7
constexpr int R_OCC    = 105;    // 21
constexpr int R_AREA   = 126;    // 3402
constexpr int R_RATE   = 3528;   // 6
constexpr int R_FU     = 3534;   // total Fu rows; row 3534 = NEW

// workspace layout (float slots)
constexpr size_t OFF_FU  = 0;                                  // 3534*64
constexpr size_t OFF_NEW = OFF_FU + (size_t)R_FU * 64;         // 64
constexpr size_t OFF_FBT = OFF_NEW + 64;                       // 64*10304 bf16 = /2 floats
constexpr size_t OFF_X   = OFF_FBT + (size_t)64 * FBTK / 2;    // 4096*64
constexpr size_t OFF_Y   = OFF_X + (size_t)BATCH * 64;
constexpr size_t OFF_P   = OFF_Y + (size_t)BATCH * 64;         // 9*4096*64
constexpr size_t OFF_C   = OFF_P + 9ull * BATCH * 64;          // 9*4096
constexpr size_t OFF_SP  = OFF_C + 9ull * BATCH;               // 256*256
constexpr size_t OFF_PB  = OFF_SP + 256ull * 256;              // 4*64
constexpr size_t OFF_SC  = OFF_PB + 4ull * 64;                 // 4*4096

// chunk tables: aligned start (for 16B-aligned B loads), valid range [vs,ve)
// invariant: (ASTART-1) % 8 == 0 ; staging zero-masks c outside [vs,ve)
__device__ const int ASTART[9] = {1, 25, 1113, 2209, 3545, 4881, 6225, 7561, 8897};
__device__ const int VSTART[9] = {1, 26, 1119, 2212, 3550, 4888, 6227, 7565, 8903};
__device__ const int VEND[9]   = {26, 1119, 2212, 3550, 4888, 6227, 7565, 8903, 10242};

typedef __attribute__((ext_vector_type(8))) short bf16x8;
typedef __attribute__((ext_vector_type(4))) float f32x4;

__device__ __forceinline__ float lrelu(float v) { return v >= 0.0f ? v : 0.01f * v; }

__device__ __forceinline__ short bf_trunc(float f) {
    return (short)(__builtin_bit_cast(unsigned, f) >> 16);
}
__device__ __forceinline__ unsigned bf_rne_pair(float lo, float hi) {
    unsigned ul = __builtin_bit_cast(unsigned, lo);
    unsigned uh = __builtin_bit_cast(unsigned, hi);
    ul += 0x7fffu + ((ul >> 16) & 1u);
    uh += 0x7fffu + ((uh >> 16) & 1u);
    return (ul >> 16) | (uh & 0xffff0000u);
}

// ---------------- K1a: fuse user-side tables (+rate) into Fu fp32; NEW row ----------------
__global__ __launch_bounds__(256) void k_fuseA(
        const float* __restrict__ gender_tab, const float* __restrict__ age_tab,
        const float* __restrict__ occ_tab, const float* __restrict__ area_tab,
        const float* __restrict__ user_W, const float* __restrict__ rate_tab,
        const float* __restrict__ item_W, const float* __restrict__ edges_tab,
        const float* __restrict__ edge_W, float* __restrict__ Fu, float* __restrict__ NEWt) {
    int t = threadIdx.x;
    int n = t & 63;
    int rb = __builtin_amdgcn_readfirstlane(t >> 6);
    int r = blockIdx.x * 4 + rb;
    if (r > R_FU) return;
    if (r == R_FU) {
        float acc = 0.0f;
#pragma unroll
        for (int k = 0; k < 64; ++k)
            acc = fmaf(edges_tab[k] * 0.12f, edge_W[k * 64 + n], acc);
        NEWt[n] = lrelu(acc);
        return;
    }
    const float* src;
    const float* W;
    if (r < R_AGE)       { src = gender_tab + (size_t)r * 64;            W = user_W;            }
    else if (r < R_OCC)  { src = age_tab    + (size_t)(r - R_AGE) * 64;  W = user_W + 64 * 64;  }
    else if (r < R_AREA) { src = occ_tab    + (size_t)(r - R_OCC) * 64;  W = user_W + 128 * 64; }
    else if (r < R_RATE) { src = area_tab   + (size_t)(r - R_AREA) * 64; W = user_W + 192 * 64; }
    else                 { src = rate_tab   + (size_t)(r - R_RATE) * 64; W = item_W;            }
    float acc = 0.0f;
#pragma unroll
    for (int k = 0; k < 64; ++k)
        acc = fmaf(src[k], W[k * 64 + n], acc);
    Fu[(size_t)r * 64 + n] = acc;
}

// ---------------- K1b: fuse item-side tables, write TRANSPOSED bf16 Fbt[64][FBTK] ----------------
// Fbt[n][KT] = fused weight for item column c = KT+1, output dim n. KT >= 10241 -> 0.
__global__ __launch_bounds__(256) void k_fuseT(
        const float* __restrict__ genre_W, const float* __restrict__ director_W,
        const float* __restrict__ actor_W, const float* __restrict__ item_W,
        short* __restrict__ Fbt) {
    const int t = threadIdx.x;
    const int KT0 = blockIdx.x * 64;
    const int n = t & 63;
    const int rb = __builtin_amdgcn_readfirstlane(t >> 6);
    __shared__ float T[64 * 65];
    for (int rl = 0; rl < 16; ++rl) {
        int r = rl * 4 + rb;
        int KT = KT0 + r;
        float acc = 0.0f;
        if (KT < 10241) {
            const float* src;
            const float* W;
            if (KT < 25)        { src = genre_W    + (size_t)KT * 64;          W = item_W + 64 * 64;  }
            else if (KT < 2211) { src = director_W + (size_t)(KT - 25) * 64;   W = item_W + 128 * 64; }
            else                { src = actor_W    + (size_t)(KT - 2211) * 64; W = item_W + 192 * 64; }
#pragma unroll
            for (int k = 0; k < 64; ++k)
                acc = fmaf(src[k], W[k * 64 + n], acc);
        }
        T[r * 65 + n] = acc;
    }
    __syncthreads();
    // transpose-pack: thread -> Fbt row n2, k-range [sg*16, sg*16+16)
    int n2 = t >> 2, sg = t & 3;
    unsigned dw[8];
#pragma unroll
    for (int d = 0; d < 8; ++d)
        dw[d] = bf_rne_pair(T[(sg * 16 + 2 * d) * 65 + n2], T[(sg * 16 + 2 * d + 1) * 65 + n2]);
    uint4* dst = (uint4*)(Fbt + (size_t)n2 * FBTK + KT0 + sg * 16);
    dst[0] = make_uint4(dw[0], dw[1], dw[2], dw[3]);
    dst[1] = make_uint4(dw[4], dw[5], dw[6], dw[7]);
}

// ---------------- K2: MFMA multi-hot GEMM + free counts ----------------
// grid (64, 9); block 256 = 4 waves; wave w -> m rows [16w,16w+16), all 64 n + count col.
__global__ __launch_bounds__(256) void k_item(const int* __restrict__ item,
                                              const short* __restrict__ Fbt,
                                              float* __restrict__ P, float* __restrict__ C) {
    const int ch = blockIdx.y;
    const int astart = ASTART[ch], vs = VSTART[ch], ve = VEND[ch];
    const int len = ve - astart;
    const int KT0 = astart - 1;            // multiple of 8
    const int m0 = blockIdx.x * 64;
    const int t = threadIdx.x;
    const int lane = t & 63;
    const int w = __builtin_amdgcn_readfirstlane(t >> 6);
    const int q = lane >> 4, r16 = lane & 15;

    __shared__ short As[64 * 136];   // A[m][k], stride 136 (+8 pad)
    __shared__ short Bs[64 * 136];   // B^T[n][k]

    f32x4 acc[5];
#pragma unroll
    for (int s = 0; s < 5; ++s) acc[s] = (f32x4){0.f, 0.f, 0.f, 0.f};

    short o = (r16 == 0) ? (short)0x3f80 : (short)0;
    bf16x8 ones = {o, o, o, o, o, o, o, o};

    for (int kb = 0; kb < len; kb += 128) {
        __syncthreads();
        // --- stage A: 64 rows x 128 cols int -> bf16 ---
        const int c0 = astart + kb;
        if (c0 >= vs && c0 + 128 <= ve) {        // interior: no masking
#pragma unroll
            for (int it = 0; it < 32; ++it) {
                int f = it * 256 + t;
                int r = f >> 7, cc = f & 127;
                int v = item[(size_t)(m0 + r) * ITEM_COLS + c0 + cc];
                As[r * 136 + cc] = bf_trunc((float)v);
            }
        } else {
#pragma unroll
            for (int it = 0; it < 32; ++it) {
                int f = it * 256 + t;
                int r = f >> 7, cc = f & 127;
                int c = c0 + cc;
                int v = (c >= vs && c < ve) ? item[(size_t)(m0 + r) * ITEM_COLS + c] : 0;
                As[r * 136 + cc] = bf_trunc((float)v);
            }
        }
        // --- stage B: 64 n-rows x 128 k bf16 from Fbt ---
        {
            int nB = t >> 2, pt = t & 3;
            const short* fb = Fbt + (size_t)nB * FBTK + KT0 + kb;
#pragma unroll
            for (int p = 0; p < 4; ++p) {
                int off = (p * 4 + pt) * 8;
                *(uint4*)(Bs + nB * 136 + off) = *(const uint4*)(fb + off);
            }
        }
        __syncthreads();
        // --- compute: 4 K-steps of 32 ---
#pragma unroll
        for (int kt = 0; kt < 4; ++kt) {
            bf16x8 a = *(const bf16x8*)(As + (w * 16 + r16) * 136 + kt * 32 + q * 8);
#pragma unroll
            for (int s = 0; s < 4; ++s) {
                bf16x8 b = *(const bf16x8*)(Bs + (s * 16 + r16) * 136 + kt * 32 + q * 8);
                acc[s] = __builtin_amdgcn_mfma_f32_16x16x32_bf16(a, b, acc[s], 0, 0, 0);
            }
            acc[4] = __builtin_amdgcn_mfma_f32_16x16x32_bf16(a, ones, acc[4], 0, 0, 0);
        }
    }
    // epilogue: D row = q*4+reg (within wave's 16), col = s*16+r16
    const size_t pb = (size_t)ch * BATCH + m0 + w * 16 + q * 4;
#pragma unroll
    for (int reg = 0; reg < 4; ++reg) {
        float* pr = P + (pb + reg) * 64 + r16;
        pr[0] = acc[0][reg];
        pr[16] = acc[1][reg];
        pr[32] = acc[2][reg];
        pr[48] = acc[3][reg];
    }
    if (r16 == 0) {
#pragma unroll
        for (int reg = 0; reg < 4; ++reg)
            C[(size_t)ch * BATCH + m0 + w * 16 + q * 4 + reg] = acc[4][reg];
    }
}

// ---------------- K3: finalize x,y, per-row dots, per-block s-partials ----------------
__device__ __forceinline__ float wred(float v) {
#pragma unroll
    for (int m = 1; m < 64; m <<= 1) v += __shfl_xor(v, m, 64);
    return v;
}

__global__ __launch_bounds__(256) void k_mid(const int* __restrict__ item, const int* __restrict__ edge_emb,
                                             const int* __restrict__ user_emb,
                                             const float* __restrict__ Fu, const float* __restrict__ user_b,
                                             const float* __restrict__ P, const float* __restrict__ C,
                                             const float* __restrict__ item_b, const float* __restrict__ edges_tab,
                                             const float* __restrict__ uu_w, const float* __restrict__ ui_w,
                                             const float* __restrict__ iu_w, const float* __restrict__ ii_w,
                                             float* __restrict__ X, float* __restrict__ Y,
                                             float* __restrict__ SC, float* __restrict__ SP) {
    const int t = threadIdx.x;
    const int n = t & 63;
    const int wv = __builtin_amdgcn_readfirstlane(t >> 6);
    const float uuw = uu_w[n], uiw = ui_w[n], iuw = iu_w[n], iiw = ii_w[n];
    const float ib = item_b[n], ub = user_b[n];
    const size_t cs = (size_t)BATCH * 64;
    float s1 = 0.0f, s2 = 0.0f, s3 = 0.0f, s4 = 0.0f;

    for (int i = 0; i < 4; ++i) {
        int b = blockIdx.x * 16 + wv * 4 + i;
        const int* ue = user_emb + (size_t)b * 4;
        float x = (Fu[(size_t)(R_GENDER + ue[0]) * 64 + n]
                 + Fu[(size_t)(R_AGE    + ue[1]) * 64 + n]
                 + Fu[(size_t)(R_OCC    + ue[2]) * 64 + n]
                 + Fu[(size_t)(R_AREA   + ue[3]) * 64 + n] + ub) * 0.12f;
        X[(size_t)b * 64 + n] = x;
        int ri = item[(size_t)b * ITEM_COLS];
        size_t base = (size_t)b * 64 + n;
        float sg = P[base];
        float sd = P[base + cs] + P[base + 2 * cs];
        float sa = P[base + 3 * cs] + P[base + 4 * cs] + P[base + 5 * cs]
                 + P[base + 6 * cs] + P[base + 7 * cs] + P[base + 8 * cs];
        float cg = C[b];
        float cd = C[BATCH + b] + C[2 * BATCH + b];
        float ca = C[3 * BATCH + b] + C[4 * BATCH + b] + C[5 * BATCH + b]
                 + C[6 * BATCH + b] + C[7 * BATCH + b] + C[8 * BATCH + b];
        float y = (Fu[(size_t)(R_RATE + ri) * 64 + n] + sg / cg + sd / cd + sa / ca + ib) * 0.12f;
        Y[(size_t)b * 64 + n] = y;
        float e = edges_tab[(size_t)edge_emb[b] * 64 + n] * 0.12f;
        float xe = x * e, ye = y * e;
        float r1 = wred(xe * uuw);  // x_xx
        float r2 = wred(xe * uiw);  // x_xy_x
        float r3 = wred(xe * iuw);  // y_yx_x
        float r4 = wred(ye * uiw);  // x_xy_y
        float r5 = wred(ye * iiw);  // y_yy
        float r6 = wred(ye * iuw);  // y_yx_y
        if (n == 0) {
            SC[b] = r1; SC[BATCH + b] = r2; SC[2 * BATCH + b] = r5; SC[3 * BATCH + b] = r6;
        }
        s1 = fmaf(r1, x, s1);
        s2 = fmaf(r4, y, s2);
        s3 = fmaf(r5, y, s3);
        s4 = fmaf(r3, x, s4);
    }
    __shared__ float sp[4][4][64];
    sp[wv][0][n] = s1; sp[wv][1][n] = s2; sp[wv][2][n] = s3; sp[wv][3][n] = s4;
    __syncthreads();
    int i2 = t >> 6;
    float v = sp[0][i2][n] + sp[1][i2][n] + sp[2][i2][n] + sp[3][i2][n];
    SP[(size_t)blockIdx.x * 256 + t] = v;
}

// ---------------- K4: reduce s-partials (256 blocks), compute p1..p4 ----------------
__global__ __launch_bounds__(1024) void k_red(const float* __restrict__ SP,
                                              const float* __restrict__ uu_W1, const float* __restrict__ ui_W1,
                                              const float* __restrict__ iu_W1, const float* __restrict__ ii_W1,
                                              float* __restrict__ PB) {
    int t = threadIdx.x;
    int sub = t >> 8, i = (t >> 6) & 3, n = t & 63;
    float s = 0.0f;
    for (int wb = sub * 64; wb < sub * 64 + 64; ++wb)
        s += SP[(size_t)wb * 256 + i * 64 + n];
    __shared__ float red[4][4][64];
    red[sub][i][n] = s;
    __syncthreads();
    float sv = red[0][i][n] + red[1][i][n] + red[2][i][n] + red[3][i][n];
    __shared__ float sl[4][64];
    if (t < 256) sl[i][n] = sv;
    __syncthreads();
    if (t < 256) {
        const float* W1 = (i == 0) ? uu_W1 : (i == 1) ? ui_W1 : (i == 2) ? ii_W1 : iu_W1;
        float p = 0.0f;
#pragma unroll
        for (int k = 0; k < 64; ++k) p = fmaf(sl[i][k], W1[k * 64 + n], p);
        PB[i * 64 + n] = p;
    }
}

// ---------------- K5: final outputs ----------------
__global__ __launch_bounds__(256) void k_out(const float* __restrict__ X, const float* __restrict__ Y,
                                             const float* __restrict__ SC, const float* __restrict__ PB,
                                             const float* __restrict__ NEWt, const float* __restrict__ edges_tab,
                                             const int* __restrict__ edge_emb, float* __restrict__ out) {
    int t = threadIdx.x;
    int b = blockIdx.x * 4 + (t >> 6);
    int n = t & 63;
    float xx = SC[b], xyx = SC[BATCH + b], yy = SC[2 * BATCH + b], yxy = SC[3 * BATCH + b];
    float p1 = PB[n], p2 = PB[64 + n], p3 = PB[128 + n], p4 = PB[192 + n];
    float x = X[(size_t)b * 64 + n], y = Y[(size_t)b * 64 + n];
    float o1 = ((lrelu(xx * p1) + lrelu(xyx * p2)) * 0.5f + x) * 0.5f;
    float o2 = ((lrelu(yy * p3) + lrelu(yxy * p4)) * 0.5f + y) * 0.5f;
    int ei = edge_emb[b];
    float e = edges_tab[(size_t)ei * 64 + n] * 0.12f;
    float o3 = (NEWt[n] + e) * 0.5f;   // edges table has 1 row; NEW row precomputed
    out[(size_t)b * 64 + n] = o1;
    out[((size_t)BATCH + b) * 64 + n] = o2;
    out[((size_t)2 * BATCH + b) * 64 + n] = o3;
}

// ---------------- launch ----------------
extern "C" void kernel_launch(void* const* d_in, const int* in_sizes, int n_in,
                              void* d_out, int out_size, void* d_ws, size_t ws_size,
                              hipStream_t stream) {
    (void)in_sizes; (void)n_in; (void)out_size; (void)ws_size;
    const int*   user_emb   = (const int*)  d_in[0];
    const int*   item_emb   = (const int*)  d_in[1];
    const int*   edge_emb   = (const int*)  d_in[2];
    const float* gender_tab = (const float*)d_in[3];
    const float* age_tab    = (const float*)d_in[4];
    const float* occ_tab    = (const float*)d_in[5];
    const float* area_tab   = (const float*)d_in[6];
    const float* user_W     = (const float*)d_in[7];
    const float* user_b     = (const float*)d_in[8];
    const float* rate_tab   = (const float*)d_in[9];
    const float* genre_W    = (const float*)d_in[10];
    const float* director_W = (const float*)d_in[11];
    const float* actor_W    = (const float*)d_in[12];
    const float* item_W     = (const float*)d_in[13];
    const float* item_b     = (const float*)d_in[14];
    const float* edges_tab  = (const float*)d_in[15];
    const float* uu_w       = (const float*)d_in[16];
    const float* ui_w       = (const float*)d_in[17];
    const float* iu_w       = (const float*)d_in[18];
    const float* ii_w       = (const float*)d_in[19];
    const float* edge_W     = (const float*)d_in[20];
    const float* uu_W1      = (const float*)d_in[21];
    const float* ui_W1      = (const float*)d_in[22];
    const float* iu_W1      = (const float*)d_in[23];
    const float* ii_W1      = (const float*)d_in[24];

    float* ws   = (float*)d_ws;
    float* Fu   = ws + OFF_FU;
    float* NEWt = ws + OFF_NEW;
    short* Fbt  = (short*)(ws + OFF_FBT);
    float* X    = ws + OFF_X;
    float* Y    = ws + OFF_Y;
    float* P    = ws + OFF_P;
    float* C    = ws + OFF_C;
    float* SP   = ws + OFF_SP;
    float* PB   = ws + OFF_PB;
    float* SC   = ws + OFF_SC;
    float* out  = (float*)d_out;

    hipLaunchKernelGGL(k_fuseA, dim3(884), dim3(256), 0, stream,
                       gender_tab, age_tab, occ_tab, area_tab, user_W, rate_tab,
                       item_W, edges_tab, edge_W, Fu, NEWt);
    hipLaunchKernelGGL(k_fuseT, dim3(FBTK / 64), dim3(256), 0, stream,
                       genre_W, director_W, actor_W, item_W, Fbt);
    hipLaunchKernelGGL(k_item, dim3(BATCH / 64, 9), dim3(256), 0, stream, item_emb, Fbt, P, C);
    hipLaunchKernelGGL(k_mid, dim3(BATCH / 16), dim3(256), 0, stream,
                       item_emb, edge_emb, user_emb, Fu, user_b, P, C, item_b, edges_tab,
                       uu_w, ui_w, iu_w, ii_w, X, Y, SC, SP);
    hipLaunchKernelGGL(k_red, dim3(1), dim3(1024), 0, stream, SP, uu_W1, ui_W1, iu_W1, ii_W1, PB);
    hipLaunchKernelGGL(k_out, dim3(BATCH / 4), dim3(256), 0, stream,
                       X, Y, SC, PB, NEWt, edges_tab, edge_emb, out);
}